// Round 1
// 4015.020 us; speedup vs baseline: 1.0366x; 1.0366x over previous
//
#include <hip/hip_runtime.h>
#include <math.h>

#define DEVFN static __device__ __forceinline__

constexpr int LAYERS = 2;
constexpr int Bz = 4;
constexpr int Cc = 256;
constexpr int Hh = 128;
constexpr int Ww = 128;
constexpr int Dd = 128;
constexpr int NHh = 2;
constexpr int BHt = Bz * NHh;              // 8
constexpr int Mt  = Hh * Ww;               // 16384
constexpr int HK = 16, WK = 16;
constexpr int NSs = HK * WK;               // 256
constexpr int STR = 8, PADc = 4;
constexpr int RPH = 2*Hh - 1, RPW = 2*Ww - 1;  // 255
constexpr float SCALE_F = 0.17677669529663687f; // 32^-0.5

typedef __attribute__((ext_vector_type(8))) short  bf16x8;
typedef __attribute__((ext_vector_type(4))) float  f32x4;

DEVFN float wsum64(float v) {
    #pragma unroll
    for (int off = 32; off > 0; off >>= 1) v += __shfl_xor(v, off, 64);
    return v;
}

// fp32 -> bf16 hi + bf16 lo (RNE both); x ~= hi + lo with ~2^-17 rel error.
DEVFN void split2(float x, ushort& h, ushort& l)
{
    const uint u  = __float_as_uint(x);
    const uint hb = (u + 0x7fffu + ((u >> 16) & 1u)) & 0xffff0000u;
    h = (ushort)(hb >> 16);
    const float r = x - __uint_as_float(hb);
    const uint ul = __float_as_uint(r);
    l = (ushort)((ul + 0x7fffu + ((ul >> 16) & 1u)) >> 16);
}

// ---------------------------------------------------------------------------
// Generic 1x1-conv projection: Out[b][o][m] = sum_c W[o][c]*X[b][c][m] + bias[o]
// grid (Mdim/64, Cc/64, Bz), block 256
// ---------------------------------------------------------------------------
__global__ __launch_bounds__(256)
void k_proj(const float* __restrict__ X, const float* __restrict__ W,
            const float* __restrict__ bias, float* __restrict__ Out, int Mdim)
{
    __shared__ float wsm[16][64];
    __shared__ float xsm[16][64];
    const int tid = threadIdx.x;
    const int m0 = blockIdx.x * 64;
    const int o0 = blockIdx.y * 64;
    const float* Xb = X + (size_t)blockIdx.z * Cc * Mdim;
    float* Ob = Out + (size_t)blockIdx.z * Cc * Mdim;
    const int to = tid >> 4;   // 0..15 (o sub /4)
    const int tm = tid & 15;   // 0..15 (m sub /4)
    float acc[4][4] = {{0.f}};
    for (int k0 = 0; k0 < Cc; k0 += 16) {
        {
            const int i = tid >> 2, kq = tid & 3;
            float4 w4 = *(const float4*)(W + (size_t)(o0 + i)*Cc + k0 + kq*4);
            wsm[kq*4+0][i] = w4.x; wsm[kq*4+1][i] = w4.y;
            wsm[kq*4+2][i] = w4.z; wsm[kq*4+3][i] = w4.w;
            const int kk = tid >> 4, jq = tid & 15;
            *(float4*)&xsm[kk][jq*4] =
                *(const float4*)(Xb + (size_t)(k0 + kk)*Mdim + m0 + jq*4);
        }
        __syncthreads();
        #pragma unroll
        for (int kk = 0; kk < 16; kk++) {
            float4 a4 = *(const float4*)&wsm[kk][to*4];
            float4 b4 = *(const float4*)&xsm[kk][tm*4];
            float av[4] = {a4.x, a4.y, a4.z, a4.w};
            float bv[4] = {b4.x, b4.y, b4.z, b4.w};
            #pragma unroll
            for (int ii = 0; ii < 4; ii++)
                #pragma unroll
                for (int jj = 0; jj < 4; jj++)
                    acc[ii][jj] += av[ii] * bv[jj];
        }
        __syncthreads();
    }
    #pragma unroll
    for (int ii = 0; ii < 4; ii++) {
        const int o = o0 + to*4 + ii;
        const float bo = bias[o];
        float4 r4 = make_float4(acc[ii][0]+bo, acc[ii][1]+bo, acc[ii][2]+bo, acc[ii][3]+bo);
        *(float4*)(Ob + (size_t)o*Mdim + m0 + tm*4) = r4;
    }
}

// ---------------------------------------------------------------------------
// Depthwise 9x9 stride-8 pad-4 conv: Y[b,c,i,j], grid (Cc, Bz), block 256
// ---------------------------------------------------------------------------
__global__ __launch_bounds__(256)
void k_dwconv(const float* __restrict__ Q, const float* __restrict__ Wdw,
              const float* __restrict__ Bdw, float* __restrict__ Y)
{
    const int c = blockIdx.x, b = blockIdx.y;
    __shared__ float wsmem[81];
    const int tid = threadIdx.x;
    if (tid < 81) wsmem[tid] = Wdw[c*81 + tid];
    __syncthreads();
    const int i = tid >> 4, j = tid & 15;
    const float* Qc = Q + ((size_t)b*Cc + c)*Mt;
    float acc = Bdw[c];
    const int ybase = i*STR - PADc, xbase = j*STR - PADc;
    #pragma unroll
    for (int u = 0; u < 9; u++) {
        const int y = ybase + u;
        if (y < 0 || y >= Hh) continue;
        #pragma unroll
        for (int v = 0; v < 9; v++) {
            const int x = xbase + v;
            if (x < 0 || x >= Ww) continue;
            acc += wsmem[u*9+v] * Qc[y*Ww + x];
        }
    }
    Y[((size_t)b*Cc + c)*NSs + i*WK + j] = acc;
}

// ---------------------------------------------------------------------------
// Channel-LN + exact GELU + pointwise(2) + ref grid -> Pos[b,s,2]
// grid (NSs, Bz), block 256 (tid = channel)
// ---------------------------------------------------------------------------
DEVFN float block_reduce(float v, float* red, int tid)
{
    red[tid] = v; __syncthreads();
    #pragma unroll
    for (int s2 = 128; s2 > 0; s2 >>= 1) {
        if (tid < s2) red[tid] += red[tid + s2];
        __syncthreads();
    }
    const float r = red[0];
    __syncthreads();
    return r;
}

__global__ __launch_bounds__(256)
void k_lnpw(const float* __restrict__ Y, const float* __restrict__ G,
            const float* __restrict__ Bt, const float* __restrict__ PW,
            float* __restrict__ Pos)
{
    __shared__ float red[256];
    const int ij = blockIdx.x, b = blockIdx.y;
    const int tid = threadIdx.x;
    const float y = Y[((size_t)b*Cc + tid)*NSs + ij];
    const float m = block_reduce(y, red, tid) * (1.f/256.f);
    const float d = y - m;
    const float v = block_reduce(d*d, red, tid) * (1.f/256.f);
    const float g = d * rsqrtf(v + 1e-5f) * G[tid] + Bt[tid];
    const float ge = 0.5f * g * (1.f + erff(g * 0.70710678118654752f));
    const float off0 = block_reduce(ge * PW[tid], red, tid);
    const float off1 = block_reduce(ge * PW[Cc + tid], red, tid);
    if (tid == 0) {
        const int i = ij >> 4, j = ij & 15;
        const float refy = ((float)i + 0.5f) * (2.f/15.f) - 1.f;
        const float refx = ((float)j + 0.5f) * (2.f/15.f) - 1.f;
        Pos[((size_t)b*NSs + ij)*2 + 0] = off0 + refy;
        Pos[((size_t)b*NSs + ij)*2 + 1] = off1 + refx;
    }
}

// ---------------------------------------------------------------------------
// Bilinear grid sample (zero padding): Xs[b,c,s] = bilerp(X[b,c], Pos[b,s])
// grid (Cc, Bz), block 256 (tid = sample index s)
// ---------------------------------------------------------------------------
__global__ __launch_bounds__(256)
void k_gsample(const float* __restrict__ X, const float* __restrict__ Pos,
               float* __restrict__ Xs)
{
    const int c = blockIdx.x, b = blockIdx.y, s = threadIdx.x;
    const float py = Pos[((size_t)b*NSs + s)*2 + 0];
    const float px = Pos[((size_t)b*NSs + s)*2 + 1];
    const float x = (px + 1.f) * 0.5f * (float)(Ww - 1);
    const float y = (py + 1.f) * 0.5f * (float)(Hh - 1);
    const float x0 = floorf(x), y0 = floorf(y);
    const float wx1 = x - x0, wx0 = 1.f - wx1;
    const float wy1 = y - y0, wy0 = 1.f - wy1;
    const float* Xc = X + ((size_t)b*Cc + c)*Mt;
    float acc = 0.f;
    #pragma unroll
    for (int t = 0; t < 4; t++) {
        const float xx = x0 + (float)(t & 1);
        const float yy = y0 + (float)(t >> 1);
        float w = ((t & 1) ? wx1 : wx0) * ((t >> 1) ? wy1 : wy0);
        const bool valid = (xx >= 0.f) && (xx <= (float)(Ww-1)) &&
                           (yy >= 0.f) && (yy <= (float)(Hh-1));
        const int xi = (int)fminf(fmaxf(xx, 0.f), (float)(Ww-1));
        const int yi = (int)fminf(fmaxf(yy, 0.f), (float)(Hh-1));
        acc += (valid ? w : 0.f) * Xc[yi*Ww + xi];
    }
    Xs[((size_t)b*Cc + c)*NSs + s] = acc;
}

// ---------------------------------------------------------------------------
// K split+transpose pre-pass: K fp32 [b][c][n] -> Kt hi/lo bf16 [bh][n][cc2]
// cc2 = stream-a ch 0..127, stream-b ch 128..255 (concat contraction dim).
// grid (NSs/64, BHt), block 256
// ---------------------------------------------------------------------------
__global__ __launch_bounds__(256)
void k_ksplit(const float* __restrict__ Ka, const float* __restrict__ Kb,
              ushort* __restrict__ KtH, ushort* __restrict__ KtL)
{
    __shared__ float tile[64][65];
    const int tid = threadIdx.x;
    const int n0 = blockIdx.x * 64;
    const int bh = blockIdx.y;
    const int b = bh >> 1, h = bh & 1;
    for (int ccblk = 0; ccblk < 4; ccblk++) {
        #pragma unroll
        for (int i = 0; i < 16; i++) {
            const int idx = i*256 + tid;
            const int ccl = idx >> 6, nl = idx & 63;
            const int cc2 = ccblk*64 + ccl;
            const float* src = (cc2 >> 7) ? Kb : Ka;
            tile[ccl][nl] = src[((size_t)b*Cc + h*Dd + (cc2 & 127))*NSs + n0 + nl];
        }
        __syncthreads();
        #pragma unroll
        for (int i = 0; i < 16; i++) {
            const int idx = i*256 + tid;
            const int nl = idx >> 6, ccl = idx & 63;
            ushort hi, lo; split2(tile[ccl][nl], hi, lo);
            const size_t o = ((size_t)bh*NSs + n0 + nl)*256 + ccblk*64 + ccl;
            KtH[o] = hi; KtL[o] = lo;
        }
        __syncthreads();
    }
}

// ---------------------------------------------------------------------------
// V split pre-pass (no transpose needed: PV contracts over n which is already
// contiguous): V fp32 [b][c][n] -> Vs hi/lo bf16 [bh][j][n], j = concat ch.
// grid (BHt*256*256/256 = 2048), block 256
// ---------------------------------------------------------------------------
__global__ __launch_bounds__(256)
void k_vsplit(const float* __restrict__ Va, const float* __restrict__ Vb,
              ushort* __restrict__ VsH, ushort* __restrict__ VsL)
{
    const size_t e = (size_t)blockIdx.x*256 + threadIdx.x;
    const int n  = (int)(e & 255);
    const int j  = (int)((e >> 8) & 255);
    const int bh = (int)(e >> 16);
    const int b = bh >> 1, h = bh & 1;
    const float* src = (j >> 7) ? Vb : Va;
    const float v = src[((size_t)b*Cc + h*Dd + (j & 127))*NSs + n];
    ushort hi, lo; split2(v, hi, lo);
    VsH[e] = hi; VsL[e] = lo;
}

// ---------------------------------------------------------------------------
// MFMA attention (bf16 hi/lo split emulation of fp32, 3 MFMAs per product):
//   S[n][m] = sum_cc Kt[n][cc]*Qt[m][cc]   (cc = 256 concat channels)
//   P = softmax_n(SCALE*S + rpe_bias)
//   O[jv][m] = sum_n Vs[jv][n]*P[m][n]     (jv = 256 concat out channels)
// Block = 64 queries, 4 waves; wave w owns m-slice w*16..w*16+15, so the
// softmax row reduction is wave-local (xor-shuffle over lanes 16,32).
// LDS: Q tile (split, [m][cc]) reused as P tile (split, [m][n]) — each wave
// overwrites only its own 16 rows, so no barrier is needed for the reuse.
// grid (Mt/64, BHt), block 256
// ---------------------------------------------------------------------------
__global__ __launch_bounds__(256, 2)
void k_attn_mfma(const float* __restrict__ Qa, const float* __restrict__ Qb,
                 const ushort* __restrict__ KtH, const ushort* __restrict__ KtL,
                 const ushort* __restrict__ VsH, const ushort* __restrict__ VsL,
                 const float* __restrict__ Pos, const float* __restrict__ Rpe,
                 float* __restrict__ Oa, float* __restrict__ Ob)
{
    constexpr int CS = 264;  // 256 + 8 pad: b128 row reads land 2-way (free)
    __shared__ __align__(16) ushort bufH[64 * CS];
    __shared__ __align__(16) ushort bufL[64 * CS];
    __shared__ float2 cxy[NSs];
    const int tid = threadIdx.x;
    const int m0 = blockIdx.x * 64;
    const int bh = blockIdx.y;
    const int b = bh >> 1, h = bh & 1;

    // per-n rpe constants: x = jq + cx[n], y = iq + cy[n]
    {
        const float py = Pos[((size_t)b*NSs + tid)*2 + 0];
        const float px = Pos[((size_t)b*NSs + tid)*2 + 1];
        cxy[tid] = make_float2(63.5f - 63.5f*px, 63.5f - 63.5f*py);
    }
    // Q tile load + split + transpose into LDS: buf[m_local][cc]
    #pragma unroll
    for (int rep = 0; rep < 16; rep++) {
        const int idx = rep*256 + tid;
        const int cc = idx >> 4, mq = idx & 15;
        const float* src = ((cc >> 7) ? Qb : Qa)
            + ((size_t)(b*Cc + h*Dd + (cc & 127)))*Mt + m0 + mq*4;
        const float4 v = *(const float4*)src;
        const float vv[4] = {v.x, v.y, v.z, v.w};
        #pragma unroll
        for (int q = 0; q < 4; q++) {
            ushort hi, lo; split2(vv[q], hi, lo);
            bufH[(mq*4+q)*CS + cc] = hi;
            bufL[(mq*4+q)*CS + cc] = lo;
        }
    }
    __syncthreads();

    const int w = tid >> 6, l = tid & 63;
    const int l15 = l & 15, g = l >> 4;

    // ---- QK^T: acc[nt] holds S[n = nt*16 + g*4 + r][m = m0 + w*16 + l15]
    f32x4 acc[16];
    #pragma unroll
    for (int nt = 0; nt < 16; nt++) acc[nt] = (f32x4){0.f, 0.f, 0.f, 0.f};

    const ushort* khp = KtH + ((size_t)bh*NSs + l15)*256 + g*8;
    const ushort* klp = KtL + ((size_t)bh*NSs + l15)*256 + g*8;
    const int qrow = (w*16 + l15)*CS + g*8;
    for (int cs = 0; cs < 8; cs++) {
        const bf16x8 qh = *(const bf16x8*)&bufH[qrow + cs*32];
        const bf16x8 ql = *(const bf16x8*)&bufL[qrow + cs*32];
        #pragma unroll
        for (int nt = 0; nt < 16; nt++) {
            const bf16x8 kh = *(const bf16x8*)(khp + nt*16*256 + cs*32);
            const bf16x8 kl = *(const bf16x8*)(klp + nt*16*256 + cs*32);
            acc[nt] = __builtin_amdgcn_mfma_f32_16x16x32_bf16(kh, qh, acc[nt], 0, 0, 0);
            acc[nt] = __builtin_amdgcn_mfma_f32_16x16x32_bf16(kh, ql, acc[nt], 0, 0, 0);
            acc[nt] = __builtin_amdgcn_mfma_f32_16x16x32_bf16(kl, qh, acc[nt], 0, 0, 0);
        }
    }

    // ---- rpe bias + softmax (rows wave-local)
    const float* Rh = Rpe + (size_t)h*RPH*RPW;
    const int m = m0 + w*16 + l15;
    const float jqf = (float)(m & 127);
    const float iqf = (float)(m >> 7);
    float mx = -1e30f;
    #pragma unroll
    for (int nt = 0; nt < 16; nt++) {
        #pragma unroll
        for (int r = 0; r < 4; r++) {
            const int n = nt*16 + g*4 + r;
            const float2 c = cxy[n];
            const float x = jqf + c.x, y = iqf + c.y;
            const float x0 = floorf(x), y0 = floorf(y);
            const float wx1 = x - x0, wx0 = 1.f - wx1;
            const float wy1 = y - y0, wy0 = 1.f - wy1;
            float bias = 0.f;
            #pragma unroll
            for (int t4 = 0; t4 < 4; t4++) {
                const float xx = x0 + (float)(t4 & 1);
                const float yy = y0 + (float)(t4 >> 1);
                const float wgt = ((t4 & 1) ? wx1 : wx0) * ((t4 >> 1) ? wy1 : wy0);
                const bool valid = (xx >= 0.f) && (xx <= (float)(RPW-1)) &&
                                   (yy >= 0.f) && (yy <= (float)(RPH-1));
                const int xi = (int)fminf(fmaxf(xx, 0.f), (float)(RPW-1));
                const int yi = (int)fminf(fmaxf(yy, 0.f), (float)(RPH-1));
                bias += (valid ? wgt : 0.f) * Rh[yi*RPW + xi];
            }
            const float s = SCALE_F*acc[nt][r] + bias;
            acc[nt][r] = s;
            mx = fmaxf(mx, s);
        }
    }
    mx = fmaxf(mx, __shfl_xor(mx, 16, 64));
    mx = fmaxf(mx, __shfl_xor(mx, 32, 64));
    float sum = 0.f;
    #pragma unroll
    for (int nt = 0; nt < 16; nt++)
        #pragma unroll
        for (int r = 0; r < 4; r++) {
            const float e = __expf(acc[nt][r] - mx);
            acc[nt][r] = e;
            sum += e;
        }
    sum += __shfl_xor(sum, 16, 64);
    sum += __shfl_xor(sum, 32, 64);
    const float inv = 1.f / sum;

    // ---- P -> LDS (split bf16), overwriting this wave's own Q rows
    const int prow = (w*16 + l15)*CS;
    #pragma unroll
    for (int nt = 0; nt < 16; nt++) {
        ushort ph[4], pl[4];
        #pragma unroll
        for (int r = 0; r < 4; r++) split2(acc[nt][r] * inv, ph[r], pl[r]);
        const int n0 = nt*16 + g*4;
        *(uint*)&bufH[prow + n0]     = (uint)ph[0] | ((uint)ph[1] << 16);
        *(uint*)&bufH[prow + n0 + 2] = (uint)ph[2] | ((uint)ph[3] << 16);
        *(uint*)&bufL[prow + n0]     = (uint)pl[0] | ((uint)pl[1] << 16);
        *(uint*)&bufL[prow + n0 + 2] = (uint)pl[2] | ((uint)pl[3] << 16);
    }

    // ---- PV: acc2[jt] holds O[jv = jt*16 + g*4 + r][m]
    f32x4 acc2[16];
    #pragma unroll
    for (int jt = 0; jt < 16; jt++) acc2[jt] = (f32x4){0.f, 0.f, 0.f, 0.f};
    const ushort* vhp = VsH + ((size_t)bh*256 + l15)*256 + g*8;
    const ushort* vlp = VsL + ((size_t)bh*256 + l15)*256 + g*8;
    for (int cs = 0; cs < 8; cs++) {
        const bf16x8 ph = *(const bf16x8*)&bufH[prow + cs*32 + g*8];
        const bf16x8 pl = *(const bf16x8*)&bufL[prow + cs*32 + g*8];
        #pragma unroll
        for (int jt = 0; jt < 16; jt++) {
            const bf16x8 vh = *(const bf16x8*)(vhp + jt*16*256 + cs*32);
            const bf16x8 vl = *(const bf16x8*)(vlp + jt*16*256 + cs*32);
            acc2[jt] = __builtin_amdgcn_mfma_f32_16x16x32_bf16(vh, ph, acc2[jt], 0, 0, 0);
            acc2[jt] = __builtin_amdgcn_mfma_f32_16x16x32_bf16(vh, pl, acc2[jt], 0, 0, 0);
            acc2[jt] = __builtin_amdgcn_mfma_f32_16x16x32_bf16(vl, ph, acc2[jt], 0, 0, 0);
        }
    }
    // ---- epilogue: token-major O (bh, M, D), 64B per row per jt
    const size_t rowbase = ((size_t)bh*Mt + m)*Dd;
    #pragma unroll
    for (int jt = 0; jt < 16; jt++) {
        const float4 o = make_float4(acc2[jt][0], acc2[jt][1], acc2[jt][2], acc2[jt][3]);
        const int jv0 = jt*16 + g*4;
        if (jt < 8) *(float4*)(Oa + rowbase + jv0) = o;
        else        *(float4*)(Ob + rowbase + jv0 - 128) = o;
    }
}

// ---------------------------------------------------------------------------
// Complex whitening LN (attention branch) + residual from (B,C,M) input.
// grid (Mt/32, BHt), block 256. X2 written token-major.
// ---------------------------------------------------------------------------
__global__ __launch_bounds__(256)
void k_cln_attn(const float* __restrict__ Oa, const float* __restrict__ Ob,
                const float* __restrict__ Xa, const float* __restrict__ Xb,
                const float* __restrict__ Pgrr, const float* __restrict__ Pgri,
                const float* __restrict__ Pgii, const float* __restrict__ Pbr,
                const float* __restrict__ Pbi,
                float* __restrict__ X2a, float* __restrict__ X2b)
{
    __shared__ float ra[32][132];
    __shared__ float rb[32][132];
    const int tid = threadIdx.x;
    const int m0 = blockIdx.x * 32;
    const int bh = blockIdx.y;
    const int b = bh >> 1, h = bh & 1;
    {
        const float* Xpa = Xa + ((size_t)b*Cc + h*Dd)*Mt + m0;
        const float* Xpb = Xb + ((size_t)b*Cc + h*Dd)*Mt + m0;
        for (int idx = tid; idx < 1024; idx += 256) {
            const int c = idx >> 3, jq = idx & 7;
            float4 a4 = *(const float4*)(Xpa + (size_t)c*Mt + jq*4);
            float4 b4 = *(const float4*)(Xpb + (size_t)c*Mt + jq*4);
            ra[jq*4+0][c] = a4.x; ra[jq*4+1][c] = a4.y;
            ra[jq*4+2][c] = a4.z; ra[jq*4+3][c] = a4.w;
            rb[jq*4+0][c] = b4.x; rb[jq*4+1][c] = b4.y;
            rb[jq*4+2][c] = b4.z; rb[jq*4+3][c] = b4.w;
        }
    }
    __syncthreads();
    const int wave = tid >> 6, lane = tid & 63;
    const float grr0 = Pgrr[lane], grr1 = Pgrr[lane+64];
    const float gri0 = Pgri[lane], gri1 = Pgri[lane+64];
    const float gii0 = Pgii[lane], gii1 = Pgii[lane+64];
    const float br0  = Pbr[lane],  br1  = Pbr[lane+64];
    const float bi0  = Pbi[lane],  bi1  = Pbi[lane+64];
    for (int r = wave; r < 32; r += 4) {
        const size_t rowoff = ((size_t)bh*Mt + m0 + r)*Dd;
        float a0 = Oa[rowoff + lane], a1 = Oa[rowoff + lane + 64];
        float c0 = Ob[rowoff + lane], c1 = Ob[rowoff + lane + 64];
        const float ma = wsum64(a0 + a1) * (1.f/128.f);
        const float mb = wsum64(c0 + c1) * (1.f/128.f);
        a0 -= ma; a1 -= ma; c0 -= mb; c1 -= mb;
        const float vrr = wsum64(a0*a0 + a1*a1) * (1.f/128.f) + 1e-20f;
        const float vii = wsum64(c0*c0 + c1*c1) * (1.f/128.f) + 1e-20f;
        const float vri = wsum64(a0*c0 + a1*c1) * (1.f/128.f);
        const float s = sqrtf(fmaxf(vrr*vii - vri*vri, 0.f));
        const float t = sqrtf(vrr + vii + 2.f*s);
        const float inv = 1.f / (s*t);
        const float wrr = (vii + s)*inv, wii = (vrr + s)*inv, wri = -vri*inv;
        const float na0 = wrr*a0 + wri*c0, nb0 = wri*a0 + wii*c0;
        const float na1 = wrr*a1 + wri*c1, nb1 = wri*a1 + wii*c1;
        X2a[rowoff + lane]      = ra[r][lane]    + grr0*na0 + gri0*nb0 + br0;
        X2a[rowoff + lane + 64] = ra[r][lane+64] + grr1*na1 + gri1*nb1 + br1;
        X2b[rowoff + lane]      = rb[r][lane]    + gri0*na0 + gii0*nb0 + bi0;
        X2b[rowoff + lane + 64] = rb[r][lane+64] + gri1*na1 + gii1*nb1 + bi1;
    }
}

// ---------------------------------------------------------------------------
// Complex linear, FULL-WIDTH blocks (64 rows x all 128 cols):
// Ha = A@Wr^T - B@Wi^T + br ; Hb = A@Wi^T + B@Wr^T + bi ; optional relu.
// Safe for in-place (Ha==A, Hb==B): a block reads only its own 64 rows, and
// all global reads complete (k-loop) before the epilogue stores.
// grid (BHt*Mt/64), block 256
// ---------------------------------------------------------------------------
__global__ __launch_bounds__(256)
void k_ffn_full(const float* __restrict__ A, const float* __restrict__ Bm,
                const float* __restrict__ Wr, const float* __restrict__ Wi,
                const float* __restrict__ br, const float* __restrict__ bi,
                float* __restrict__ Ha, float* __restrict__ Hb, int relu)
{
    __shared__ float as_[16][64], bs_[16][64];
    __shared__ float wrs[16][128], wis[16][128];
    const int tid = threadIdx.x;
    const size_t r0 = (size_t)blockIdx.x * 64;
    const int tr = tid >> 4;   // 0..15: rows tr*4+ii
    const int tn = tid & 15;   // 0..15: cols tn*8+jj
    float accr[4][8] = {{0.f}}, acci[4][8] = {{0.f}};
    for (int k0 = 0; k0 < Dd; k0 += 16) {
        {
            const int row = tid >> 2, kq = tid & 3;
            float4 a4 = *(const float4*)(A  + (r0 + row)*Dd + k0 + kq*4);
            float4 b4 = *(const float4*)(Bm + (r0 + row)*Dd + k0 + kq*4);
            as_[kq*4+0][row] = a4.x; as_[kq*4+1][row] = a4.y;
            as_[kq*4+2][row] = a4.z; as_[kq*4+3][row] = a4.w;
            bs_[kq*4+0][row] = b4.x; bs_[kq*4+1][row] = b4.y;
            bs_[kq*4+2][row] = b4.z; bs_[kq*4+3][row] = b4.w;
            #pragma unroll
            for (int rep = 0; rep < 2; rep++) {
                const int wrow = row + rep*64;
                float4 r4 = *(const float4*)(Wr + (size_t)wrow*Dd + k0 + kq*4);
                float4 i4 = *(const float4*)(Wi + (size_t)wrow*Dd + k0 + kq*4);
                wrs[kq*4+0][wrow] = r4.x; wrs[kq*4+1][wrow] = r4.y;
                wrs[kq*4+2][wrow] = r4.z; wrs[kq*4+3][wrow] = r4.w;
                wis[kq*4+0][wrow] = i4.x; wis[kq*4+1][wrow] = i4.y;
                wis[kq*4+2][wrow] = i4.z; wis[kq*4+3][wrow] = i4.w;
            }
        }
        __syncthreads();
        #pragma unroll
        for (int kk = 0; kk < 16; kk++) {
            float4 a4 = *(const float4*)&as_[kk][tr*4];
            float4 b4 = *(const float4*)&bs_[kk][tr*4];
            float4 r40 = *(const float4*)&wrs[kk][tn*8];
            float4 r41 = *(const float4*)&wrs[kk][tn*8+4];
            float4 i40 = *(const float4*)&wis[kk][tn*8];
            float4 i41 = *(const float4*)&wis[kk][tn*8+4];
            float av[4] = {a4.x,a4.y,a4.z,a4.w};
            float bv[4] = {b4.x,b4.y,b4.z,b4.w};
            float rv[8] = {r40.x,r40.y,r40.z,r40.w,r41.x,r41.y,r41.z,r41.w};
            float iv[8] = {i40.x,i40.y,i40.z,i40.w,i41.x,i41.y,i41.z,i41.w};
            #pragma unroll
            for (int ii = 0; ii < 4; ii++)
                #pragma unroll
                for (int jj = 0; jj < 8; jj++) {
                    accr[ii][jj] += av[ii]*rv[jj] - bv[ii]*iv[jj];
                    acci[ii][jj] += av[ii]*iv[jj] + bv[ii]*rv[jj];
                }
        }
        __syncthreads();
    }
    #pragma unroll
    for (int ii = 0; ii < 4; ii++) {
        const size_t row = r0 + tr*4 + ii;
        #pragma unroll
        for (int jq = 0; jq < 2; jq++) {
            float4 vr, vi;
            float* pr = &vr.x; float* pi = &vi.x;
            #pragma unroll
            for (int q = 0; q < 4; q++) {
                const int n = tn*8 + jq*4 + q;
                float hr = accr[ii][jq*4+q] + br[n];
                float hi = acci[ii][jq*4+q] + bi[n];
                if (relu) { hr = fmaxf(hr, 0.f); hi = fmaxf(hi, 0.f); }
                pr[q] = hr; pi[q] = hi;
            }
            *(float4*)(Ha + row*Dd + tn*8 + jq*4) = vr;
            *(float4*)(Hb + row*Dd + tn*8 + jq*4) = vi;
        }
    }
}

// ---------------------------------------------------------------------------
// Complex whitening LN (FFN branch) + residual (token-major) + transpose out
// to (B,C,M). grid (Mt/32, BHt), block 256
// ---------------------------------------------------------------------------
__global__ __launch_bounds__(256)
void k_cln_ffn(const float* __restrict__ Ha2, const float* __restrict__ Hb2,
               const float* __restrict__ X2a, const float* __restrict__ X2b,
               const float* __restrict__ Pgrr, const float* __restrict__ Pgri,
               const float* __restrict__ Pgii, const float* __restrict__ Pbr,
               const float* __restrict__ Pbi,
               float* __restrict__ OutA, float* __restrict__ OutB)
{
    __shared__ float oA[128][36];
    __shared__ float oB[128][36];
    const int tid = threadIdx.x;
    const int m0 = blockIdx.x * 32;
    const int bh = blockIdx.y;
    const int b = bh >> 1, h = bh & 1;
    const int wave = tid >> 6, lane = tid & 63;
    const float grr0 = Pgrr[lane], grr1 = Pgrr[lane+64];
    const float gri0 = Pgri[lane], gri1 = Pgri[lane+64];
    const float gii0 = Pgii[lane], gii1 = Pgii[lane+64];
    const float br0  = Pbr[lane],  br1  = Pbr[lane+64];
    const float bi0  = Pbi[lane],  bi1  = Pbi[lane+64];
    for (int r = wave; r < 32; r += 4) {
        const size_t rowoff = ((size_t)bh*Mt + m0 + r)*Dd;
        float a0 = Ha2[rowoff + lane], a1 = Ha2[rowoff + lane + 64];
        float c0 = Hb2[rowoff + lane], c1 = Hb2[rowoff + lane + 64];
        const float ma = wsum64(a0 + a1) * (1.f/128.f);
        const float mb = wsum64(c0 + c1) * (1.f/128.f);
        a0 -= ma; a1 -= ma; c0 -= mb; c1 -= mb;
        const float vrr = wsum64(a0*a0 + a1*a1) * (1.f/128.f) + 1e-20f;
        const float vii = wsum64(c0*c0 + c1*c1) * (1.f/128.f) + 1e-20f;
        const float vri = wsum64(a0*c0 + a1*c1) * (1.f/128.f);
        const float s = sqrtf(fmaxf(vrr*vii - vri*vri, 0.f));
        const float t = sqrtf(vrr + vii + 2.f*s);
        const float inv = 1.f / (s*t);
        const float wrr = (vii + s)*inv, wii = (vrr + s)*inv, wri = -vri*inv;
        const float na0 = wrr*a0 + wri*c0, nb0 = wri*a0 + wii*c0;
        const float na1 = wrr*a1 + wri*c1, nb1 = wri*a1 + wii*c1;
        oA[lane][r]    = X2a[rowoff + lane]      + grr0*na0 + gri0*nb0 + br0;
        oA[lane+64][r] = X2a[rowoff + lane + 64] + grr1*na1 + gri1*nb1 + br1;
        oB[lane][r]    = X2b[rowoff + lane]      + gri0*na0 + gii0*nb0 + bi0;
        oB[lane+64][r] = X2b[rowoff + lane + 64] + gri1*na1 + gii1*nb1 + bi1;
    }
    __syncthreads();
    const size_t obase = ((size_t)b*Cc + h*Dd)*Mt + m0;
    for (int idx = tid; idx < 1024; idx += 256) {
        const int c = idx >> 3, jq = idx & 7;
        *(float4*)(OutA + obase + (size_t)c*Mt + jq*4) = *(const float4*)&oA[c][jq*4];
        *(float4*)(OutB + obase + (size_t)c*Mt + jq*4) = *(const float4*)&oB[c][jq*4];
    }
}

// ---------------------------------------------------------------------------
extern "C" void kernel_launch(void* const* d_in, const int* in_sizes, int n_in,
                              void* d_out, int out_size, void* d_ws, size_t ws_size,
                              hipStream_t stream)
{
    const float* xA0 = (const float*)d_in[0];
    const float* xB0 = (const float*)d_in[1];
    const float* wq  = (const float*)d_in[2];
    const float* bq  = (const float*)d_in[3];
    const float* wk  = (const float*)d_in[4];
    const float* bk  = (const float*)d_in[5];
    const float* wv  = (const float*)d_in[6];
    const float* bv  = (const float*)d_in[7];
    const float* dww = (const float*)d_in[8];
    const float* dwb = (const float*)d_in[9];
    const float* lng = (const float*)d_in[10];
    const float* lnb = (const float*)d_in[11];
    const float* pw  = (const float*)d_in[12];
    const float* f1wr = (const float*)d_in[13];
    const float* f1wi = (const float*)d_in[14];
    const float* f1br = (const float*)d_in[15];
    const float* f1bi = (const float*)d_in[16];
    const float* f2wr = (const float*)d_in[17];
    const float* f2wi = (const float*)d_in[18];
    const float* f2br = (const float*)d_in[19];
    const float* f2bi = (const float*)d_in[20];
    const float* lgrr = (const float*)d_in[21];
    const float* lgri = (const float*)d_in[22];
    const float* lgii = (const float*)d_in[23];
    const float* lbr  = (const float*)d_in[24];
    const float* lbi  = (const float*)d_in[25];
    const float* rpe  = (const float*)d_in[26];

    float* ws = (float*)d_ws;
    const size_t NB = (size_t)Bz * Cc * Mt;     // 16777216 floats (64 MB)
    const size_t SC = (size_t)Bz * Cc * NSs;    // 262144 floats (1 MB)
    // Compact layout: 2 big pairs (P: Q then X2; R: O then H1/H2) = 256 MB,
    // plus ~11 MB of small buffers. Layer chaining goes through d_out.
    float* Pa  = ws;        float* Pb  = Pa  + NB;
    float* Ra  = Pb  + NB;  float* Rb  = Ra  + NB;
    float* Ya  = Rb  + NB;  float* Yb  = Ya  + SC;
    float* XsA = Yb  + SC;  float* XsB = XsA + SC;
    float* Kab = XsB + SC;  float* Kbb = Kab + SC;
    float* Vab = Kbb + SC;  float* Vbb = Vab + SC;
    float* Sp0 = Vbb + SC;  float* Sp1 = Sp0 + SC;  // bf16 K split regions
    float* PosA = Sp1 + SC; float* PosB = PosA + (size_t)Bz*NSs*2;

    // bf16 hi/lo buffers (each 8*256*256 ushorts = 1 MB):
    // K reuses the two spare SC regions; V reuses Ya/Yb (dead after k_lnpw,
    // and k_vsplit runs after k_lnpw in program order).
    ushort* KtH = (ushort*)Sp0;
    ushort* KtL = (ushort*)Sp1;
    ushort* VsH = (ushort*)Ya;
    ushort* VsL = (ushort*)Yb;

    float* outAf = (float*)d_out;
    float* outBf = outAf + NB;

    for (int l = 0; l < LAYERS; l++) {
        const float* pwq = wq + (size_t)l*Cc*Cc;
        const float* pbq = bq + (size_t)l*Cc;
        const float* pwk = wk + (size_t)l*Cc*Cc;
        const float* pbk = bk + (size_t)l*Cc;
        const float* pwv = wv + (size_t)l*Cc*Cc;
        const float* pbv = bv + (size_t)l*Cc;
        const float* pdww = dww + (size_t)l*Cc*81;
        const float* pdwb = dwb + (size_t)l*Cc;
        const float* plng = lng + (size_t)l*Cc;
        const float* plnb = lnb + (size_t)l*Cc;
        const float* ppw  = pw  + (size_t)l*2*Cc;
        const float* p1wr = f1wr + (size_t)l*Dd*Dd;
        const float* p1wi = f1wi + (size_t)l*Dd*Dd;
        const float* p1br = f1br + (size_t)l*Dd;
        const float* p1bi = f1bi + (size_t)l*Dd;
        const float* p2wr = f2wr + (size_t)l*Dd*Dd;
        const float* p2wi = f2wi + (size_t)l*Dd*Dd;
        const float* p2br = f2br + (size_t)l*Dd;
        const float* p2bi = f2bi + (size_t)l*Dd;
        const float* g0rr = lgrr + (size_t)(l*2+0)*Dd;
        const float* g0ri = lgri + (size_t)(l*2+0)*Dd;
        const float* g0ii = lgii + (size_t)(l*2+0)*Dd;
        const float* g0br = lbr  + (size_t)(l*2+0)*Dd;
        const float* g0bi = lbi  + (size_t)(l*2+0)*Dd;
        const float* g1rr = lgrr + (size_t)(l*2+1)*Dd;
        const float* g1ri = lgri + (size_t)(l*2+1)*Dd;
        const float* g1ii = lgii + (size_t)(l*2+1)*Dd;
        const float* g1br = lbr  + (size_t)(l*2+1)*Dd;
        const float* g1bi = lbi  + (size_t)(l*2+1)*Dd;
        const float* prpe = rpe + (size_t)l*NHh*RPH*RPW;

        const float* inA = l ? outAf : xA0;
        const float* inB = l ? outBf : xB0;

        // Q -> P
        dim3 gP(Mt/64, Cc/64, Bz);
        k_proj<<<gP, 256, 0, stream>>>(inA, pwq, pbq, Pa, Mt);
        k_proj<<<gP, 256, 0, stream>>>(inB, pwq, pbq, Pb, Mt);

        dim3 gD(Cc, Bz);
        k_dwconv<<<gD, 256, 0, stream>>>(Pa, pdww, pdwb, Ya);
        k_dwconv<<<gD, 256, 0, stream>>>(Pb, pdww, pdwb, Yb);

        dim3 gL(NSs, Bz);
        k_lnpw<<<gL, 256, 0, stream>>>(Ya, plng, plnb, ppw, PosA);
        k_lnpw<<<gL, 256, 0, stream>>>(Yb, plng, plnb, ppw, PosB);

        dim3 gS(Cc, Bz);
        k_gsample<<<gS, 256, 0, stream>>>(inA, PosA, XsA);
        k_gsample<<<gS, 256, 0, stream>>>(inB, PosB, XsB);

        dim3 gKV(NSs/64, Cc/64, Bz);
        k_proj<<<gKV, 256, 0, stream>>>(XsA, pwk, pbk, Kab, NSs);
        k_proj<<<gKV, 256, 0, stream>>>(XsB, pwk, pbk, Kbb, NSs);
        k_proj<<<gKV, 256, 0, stream>>>(XsA, pwv, pbv, Vab, NSs);
        k_proj<<<gKV, 256, 0, stream>>>(XsB, pwv, pbv, Vbb, NSs);

        // bf16 hi/lo pre-splits for MFMA attention (Ya/Yb dead by now)
        dim3 gKs(NSs/64, BHt);
        k_ksplit<<<gKs, 256, 0, stream>>>(Kab, Kbb, KtH, KtL);
        k_vsplit<<<2048, 256, 0, stream>>>(Vab, Vbb, VsH, VsL);

        // attn: Q(P) -> O(R).  Q dead afterwards.
        dim3 gA(Mt/64, BHt);
        k_attn_mfma<<<gA, 256, 0, stream>>>(Pa, Pb, KtH, KtL, VsH, VsL,
                                            PosA, prpe, Ra, Rb);

        // cln_attn: O(R) + X(in) -> X2(P).  O dead afterwards.
        dim3 gC(Mt/32, BHt);
        k_cln_attn<<<gC, 256, 0, stream>>>(Ra, Rb, inA, inB,
                                           g0rr, g0ri, g0ii, g0br, g0bi, Pa, Pb);

        // fc1: X2(P) -> H1(R); fc2: H1(R) -> H2(R) in-place.
        dim3 gF((unsigned)((size_t)BHt*Mt/64));
        k_ffn_full<<<gF, 256, 0, stream>>>(Pa, Pb, p1wr, p1wi, p1br, p1bi, Ra, Rb, 1);
        k_ffn_full<<<gF, 256, 0, stream>>>(Ra, Rb, p2wr, p2wi, p2br, p2bi, Ra, Rb, 0);

        // cln_ffn: H2(R) + X2(P) -> layer output (d_out; safe: inA not read here)
        k_cln_ffn<<<gC, 256, 0, stream>>>(Ra, Rb, Pa, Pb,
                                          g1rr, g1ri, g1ii, g1br, g1bi, outAf, outBf);
    }
    (void)in_sizes; (void)n_in; (void)out_size; (void)ws_size;
}

// Round 2
// 4004.670 us; speedup vs baseline: 1.0393x; 1.0026x over previous
//
#include <hip/hip_runtime.h>
#include <math.h>

#define DEVFN static __device__ __forceinline__

constexpr int LAYERS = 2;
constexpr int Bz = 4;
constexpr int Cc = 256;
constexpr int Hh = 128;
constexpr int Ww = 128;
constexpr int Dd = 128;
constexpr int NHh = 2;
constexpr int BHt = Bz * NHh;              // 8
constexpr int Mt  = Hh * Ww;               // 16384
constexpr int HK = 16, WK = 16;
constexpr int NSs = HK * WK;               // 256
constexpr int STR = 8, PADc = 4;
constexpr int RPH = 2*Hh - 1, RPW = 2*Ww - 1;  // 255
constexpr float SCALE_F = 0.17677669529663687f; // 32^-0.5

typedef __attribute__((ext_vector_type(8))) short  bf16x8;
typedef __attribute__((ext_vector_type(4))) float  f32x4;

DEVFN float wsum64(float v) {
    #pragma unroll
    for (int off = 32; off > 0; off >>= 1) v += __shfl_xor(v, off, 64);
    return v;
}

// fp32 -> bf16 hi + bf16 lo (RNE both); x ~= hi + lo with ~2^-17 rel error.
DEVFN void split2(float x, ushort& h, ushort& l)
{
    const uint u  = __float_as_uint(x);
    const uint hb = (u + 0x7fffu + ((u >> 16) & 1u)) & 0xffff0000u;
    h = (ushort)(hb >> 16);
    const float r = x - __uint_as_float(hb);
    const uint ul = __float_as_uint(r);
    l = (ushort)((ul + 0x7fffu + ((ul >> 16) & 1u)) >> 16);
}

DEVFN uint shfu(uint v, int src) { return (uint)__shfl((int)v, src, 64); }

DEVFN bf16x8 pack4(uint a, uint b, uint c, uint d)
{
    union { uint u[4]; bf16x8 v; } t;
    t.u[0] = a; t.u[1] = b; t.u[2] = c; t.u[3] = d;
    return t.v;
}

// ---------------------------------------------------------------------------
// Generic 1x1-conv projection: Out[b][o][m] = sum_c W[o][c]*X[b][c][m] + bias[o]
// grid (Mdim/64, Cc/64, Bz), block 256
// ---------------------------------------------------------------------------
__global__ __launch_bounds__(256)
void k_proj(const float* __restrict__ X, const float* __restrict__ W,
            const float* __restrict__ bias, float* __restrict__ Out, int Mdim)
{
    __shared__ float wsm[16][64];
    __shared__ float xsm[16][64];
    const int tid = threadIdx.x;
    const int m0 = blockIdx.x * 64;
    const int o0 = blockIdx.y * 64;
    const float* Xb = X + (size_t)blockIdx.z * Cc * Mdim;
    float* Ob = Out + (size_t)blockIdx.z * Cc * Mdim;
    const int to = tid >> 4;   // 0..15 (o sub /4)
    const int tm = tid & 15;   // 0..15 (m sub /4)
    float acc[4][4] = {{0.f}};
    for (int k0 = 0; k0 < Cc; k0 += 16) {
        {
            const int i = tid >> 2, kq = tid & 3;
            float4 w4 = *(const float4*)(W + (size_t)(o0 + i)*Cc + k0 + kq*4);
            wsm[kq*4+0][i] = w4.x; wsm[kq*4+1][i] = w4.y;
            wsm[kq*4+2][i] = w4.z; wsm[kq*4+3][i] = w4.w;
            const int kk = tid >> 4, jq = tid & 15;
            *(float4*)&xsm[kk][jq*4] =
                *(const float4*)(Xb + (size_t)(k0 + kk)*Mdim + m0 + jq*4);
        }
        __syncthreads();
        #pragma unroll
        for (int kk = 0; kk < 16; kk++) {
            float4 a4 = *(const float4*)&wsm[kk][to*4];
            float4 b4 = *(const float4*)&xsm[kk][tm*4];
            float av[4] = {a4.x, a4.y, a4.z, a4.w};
            float bv[4] = {b4.x, b4.y, b4.z, b4.w};
            #pragma unroll
            for (int ii = 0; ii < 4; ii++)
                #pragma unroll
                for (int jj = 0; jj < 4; jj++)
                    acc[ii][jj] += av[ii] * bv[jj];
        }
        __syncthreads();
    }
    #pragma unroll
    for (int ii = 0; ii < 4; ii++) {
        const int o = o0 + to*4 + ii;
        const float bo = bias[o];
        float4 r4 = make_float4(acc[ii][0]+bo, acc[ii][1]+bo, acc[ii][2]+bo, acc[ii][3]+bo);
        *(float4*)(Ob + (size_t)o*Mdim + m0 + tm*4) = r4;
    }
}

// ---------------------------------------------------------------------------
// Depthwise 9x9 stride-8 pad-4 conv: Y[b,c,i,j], grid (Cc, Bz), block 256
// ---------------------------------------------------------------------------
__global__ __launch_bounds__(256)
void k_dwconv(const float* __restrict__ Q, const float* __restrict__ Wdw,
              const float* __restrict__ Bdw, float* __restrict__ Y)
{
    const int c = blockIdx.x, b = blockIdx.y;
    __shared__ float wsmem[81];
    const int tid = threadIdx.x;
    if (tid < 81) wsmem[tid] = Wdw[c*81 + tid];
    __syncthreads();
    const int i = tid >> 4, j = tid & 15;
    const float* Qc = Q + ((size_t)b*Cc + c)*Mt;
    float acc = Bdw[c];
    const int ybase = i*STR - PADc, xbase = j*STR - PADc;
    #pragma unroll
    for (int u = 0; u < 9; u++) {
        const int y = ybase + u;
        if (y < 0 || y >= Hh) continue;
        #pragma unroll
        for (int v = 0; v < 9; v++) {
            const int x = xbase + v;
            if (x < 0 || x >= Ww) continue;
            acc += wsmem[u*9+v] * Qc[y*Ww + x];
        }
    }
    Y[((size_t)b*Cc + c)*NSs + i*WK + j] = acc;
}

// ---------------------------------------------------------------------------
// Channel-LN + exact GELU + pointwise(2) + ref grid -> Pos[b,s,2]
// grid (NSs, Bz), block 256 (tid = channel)
// ---------------------------------------------------------------------------
DEVFN float block_reduce(float v, float* red, int tid)
{
    red[tid] = v; __syncthreads();
    #pragma unroll
    for (int s2 = 128; s2 > 0; s2 >>= 1) {
        if (tid < s2) red[tid] += red[tid + s2];
        __syncthreads();
    }
    const float r = red[0];
    __syncthreads();
    return r;
}

__global__ __launch_bounds__(256)
void k_lnpw(const float* __restrict__ Y, const float* __restrict__ G,
            const float* __restrict__ Bt, const float* __restrict__ PW,
            float* __restrict__ Pos)
{
    __shared__ float red[256];
    const int ij = blockIdx.x, b = blockIdx.y;
    const int tid = threadIdx.x;
    const float y = Y[((size_t)b*Cc + tid)*NSs + ij];
    const float m = block_reduce(y, red, tid) * (1.f/256.f);
    const float d = y - m;
    const float v = block_reduce(d*d, red, tid) * (1.f/256.f);
    const float g = d * rsqrtf(v + 1e-5f) * G[tid] + Bt[tid];
    const float ge = 0.5f * g * (1.f + erff(g * 0.70710678118654752f));
    const float off0 = block_reduce(ge * PW[tid], red, tid);
    const float off1 = block_reduce(ge * PW[Cc + tid], red, tid);
    if (tid == 0) {
        const int i = ij >> 4, j = ij & 15;
        const float refy = ((float)i + 0.5f) * (2.f/15.f) - 1.f;
        const float refx = ((float)j + 0.5f) * (2.f/15.f) - 1.f;
        Pos[((size_t)b*NSs + ij)*2 + 0] = off0 + refy;
        Pos[((size_t)b*NSs + ij)*2 + 1] = off1 + refx;
    }
}

// ---------------------------------------------------------------------------
// Bilinear grid sample (zero padding): Xs[b,c,s] = bilerp(X[b,c], Pos[b,s])
// grid (Cc, Bz), block 256 (tid = sample index s)
// ---------------------------------------------------------------------------
__global__ __launch_bounds__(256)
void k_gsample(const float* __restrict__ X, const float* __restrict__ Pos,
               float* __restrict__ Xs)
{
    const int c = blockIdx.x, b = blockIdx.y, s = threadIdx.x;
    const float py = Pos[((size_t)b*NSs + s)*2 + 0];
    const float px = Pos[((size_t)b*NSs + s)*2 + 1];
    const float x = (px + 1.f) * 0.5f * (float)(Ww - 1);
    const float y = (py + 1.f) * 0.5f * (float)(Hh - 1);
    const float x0 = floorf(x), y0 = floorf(y);
    const float wx1 = x - x0, wx0 = 1.f - wx1;
    const float wy1 = y - y0, wy0 = 1.f - wy1;
    const float* Xc = X + ((size_t)b*Cc + c)*Mt;
    float acc = 0.f;
    #pragma unroll
    for (int t = 0; t < 4; t++) {
        const float xx = x0 + (float)(t & 1);
        const float yy = y0 + (float)(t >> 1);
        float w = ((t & 1) ? wx1 : wx0) * ((t >> 1) ? wy1 : wy0);
        const bool valid = (xx >= 0.f) && (xx <= (float)(Ww-1)) &&
                           (yy >= 0.f) && (yy <= (float)(Hh-1));
        const int xi = (int)fminf(fmaxf(xx, 0.f), (float)(Ww-1));
        const int yi = (int)fminf(fmaxf(yy, 0.f), (float)(Hh-1));
        acc += (valid ? w : 0.f) * Xc[yi*Ww + xi];
    }
    Xs[((size_t)b*Cc + c)*NSs + s] = acc;
}

// ---------------------------------------------------------------------------
// K split+transpose pre-pass: K fp32 [b][c][n] -> Kt hi/lo bf16 [bh][n][cc2]
// cc2 = stream-a ch 0..127, stream-b ch 128..255 (concat contraction dim).
// grid (NSs/64, BHt), block 256
// ---------------------------------------------------------------------------
__global__ __launch_bounds__(256)
void k_ksplit(const float* __restrict__ Ka, const float* __restrict__ Kb,
              ushort* __restrict__ KtH, ushort* __restrict__ KtL)
{
    __shared__ float tile[64][65];
    const int tid = threadIdx.x;
    const int n0 = blockIdx.x * 64;
    const int bh = blockIdx.y;
    const int b = bh >> 1, h = bh & 1;
    for (int ccblk = 0; ccblk < 4; ccblk++) {
        #pragma unroll
        for (int i = 0; i < 16; i++) {
            const int idx = i*256 + tid;
            const int ccl = idx >> 6, nl = idx & 63;
            const int cc2 = ccblk*64 + ccl;
            const float* src = (cc2 >> 7) ? Kb : Ka;
            tile[ccl][nl] = src[((size_t)b*Cc + h*Dd + (cc2 & 127))*NSs + n0 + nl];
        }
        __syncthreads();
        #pragma unroll
        for (int i = 0; i < 16; i++) {
            const int idx = i*256 + tid;
            const int nl = idx >> 6, ccl = idx & 63;
            ushort hi, lo; split2(tile[ccl][nl], hi, lo);
            const size_t o = ((size_t)bh*NSs + n0 + nl)*256 + ccblk*64 + ccl;
            KtH[o] = hi; KtL[o] = lo;
        }
        __syncthreads();
    }
}

// ---------------------------------------------------------------------------
// V split pre-pass (no transpose needed: PV contracts over n which is already
// contiguous): V fp32 [b][c][n] -> Vs hi/lo bf16 [bh][j][n], j = concat ch.
// grid (BHt*256*256/256 = 2048), block 256
// ---------------------------------------------------------------------------
__global__ __launch_bounds__(256)
void k_vsplit(const float* __restrict__ Va, const float* __restrict__ Vb,
              ushort* __restrict__ VsH, ushort* __restrict__ VsL)
{
    const size_t e = (size_t)blockIdx.x*256 + threadIdx.x;
    const int n  = (int)(e & 255);
    const int j  = (int)((e >> 8) & 255);
    const int bh = (int)(e >> 16);
    const int b = bh >> 1, h = bh & 1;
    const float* src = (j >> 7) ? Vb : Va;
    const float v = src[((size_t)b*Cc + h*Dd + (j & 127))*NSs + n];
    ushort hi, lo; split2(v, hi, lo);
    VsH[e] = hi; VsL[e] = lo;
}

// ---------------------------------------------------------------------------
// MFMA attention v2.
//   S[n][m] = sum_cc Kt[n][cc]*Q[m][cc]   (hi/lo bf16 split, 3 MFMAs/product)
//   P = softmax_n(SCALE*S + rpe_bias)
//   O[jv][m] = sum_n Vs[jv][n]*P[m][n]
// Changes vs v1:
//  * rpe bias via per-block separable G-table in LDS: bias(m,n) =
//    (1-fx[n])*G[n][dm] + fx[n]*G[n][dm+1]  (dm = m - m0).  G built once per
//    block from CONTIGUOUS rpe-row reads (y-lerp + zero-pad folded in).
//    Replaces 256 scattered global gathers per thread with 2 LDS reads/elem.
//  * Q loaded global->register directly (no LDS staging, no ds_write_b16
//    conflicts).
//  * P softmax->PV fragment redistribution in-register via __shfl among the
//    4 lanes {g} sharing l15 (derived from the validated fragment mapping:
//    target (g,l15) elem j of k-slice cs comes from lane gs=(2g+(j>>2))&3,
//    its packed word [2cs + (g>>1)]).
// LDS = G-table 67.6KB + fx 1KB -> 2 blocks/CU.
// grid (Mt/64, BHt), block 256
// ---------------------------------------------------------------------------
__global__ __launch_bounds__(256, 2)
void k_attn_mfma(const float* __restrict__ Qa, const float* __restrict__ Qb,
                 const ushort* __restrict__ KtH, const ushort* __restrict__ KtL,
                 const ushort* __restrict__ VsH, const ushort* __restrict__ VsL,
                 const float* __restrict__ Pos, const float* __restrict__ Rpe,
                 float* __restrict__ Oa, float* __restrict__ Ob)
{
    constexpr int GS = 66;                 // 65 entries + 1 pad (2-way banks)
    __shared__ float Gt[NSs * GS];         // 67584 B
    __shared__ float fxs[NSs];             // 1024 B
    const int tid = threadIdx.x;
    const int m0 = blockIdx.x * 64;
    const int bh = blockIdx.y;
    const int b = bh >> 1, h = bh & 1;
    const int j0 = m0 & 127;               // jq base for this block (0 or 64)
    const int iq = m0 >> 7;                // constant over the block
    const float* Rh = Rpe + (size_t)h * RPH * RPW;

    // ---- G-table build: thread n handles sample n (contiguous row reads)
    {
        const int n = tid;
        const float py = Pos[((size_t)b*NSs + n)*2 + 0];
        const float px = Pos[((size_t)b*NSs + n)*2 + 1];
        const float xf = (float)j0 + 63.5f - 63.5f*px;   // x(m) = xf + dm
        const float yf = (float)iq + 63.5f - 63.5f*py;   // y const over block
        const float xbf = floorf(xf), ybf = floorf(yf);
        const float fx = xf - xbf, fy = yf - ybf;
        fxs[n] = fx;
        const int yb = (int)ybf;
        const float wy0 = (1.f - fy) * ((yb   >= 0 && yb   <= RPH-1) ? 1.f : 0.f);
        const float wy1 = fy         * ((yb+1 >= 0 && yb+1 <= RPH-1) ? 1.f : 0.f);
        const int y0c = yb   < 0 ? 0 : (yb   > RPH-1 ? RPH-1 : yb);
        const int y1c = yb+1 < 0 ? 0 : (yb+1 > RPH-1 ? RPH-1 : yb+1);
        const float* r0 = Rh + (size_t)y0c * RPW;
        const float* r1 = Rh + (size_t)y1c * RPW;
        const int xb = (int)xbf;
        for (int t = 0; t <= 64; t++) {
            const int xi = xb + t;
            const int xc = xi < 0 ? 0 : (xi > RPW-1 ? RPW-1 : xi);
            const float v = wy0*r0[xc] + wy1*r1[xc];
            Gt[n*GS + t] = (xi >= 0 && xi <= RPW-1) ? v : 0.f;
        }
    }

    const int w = tid >> 6, l = tid & 63;
    const int l15 = l & 15, g = l >> 4;
    const int mcol = m0 + w*16 + l15;      // this lane's output column m

    // ---- QK^T: acc[nt] holds S[n = nt*16 + g*4 + r][m = mcol]
    f32x4 acc[16];
    #pragma unroll
    for (int nt = 0; nt < 16; nt++) acc[nt] = (f32x4){0.f, 0.f, 0.f, 0.f};

    const float* qbaseA = Qa + ((size_t)(b*Cc + h*Dd))*Mt + mcol;
    const float* qbaseB = Qb + ((size_t)(b*Cc + h*Dd))*Mt + mcol;
    const ushort* khp = KtH + ((size_t)bh*NSs + l15)*256 + g*8;
    const ushort* klp = KtL + ((size_t)bh*NSs + l15)*256 + g*8;

    #pragma unroll
    for (int cs = 0; cs < 8; cs++) {
        const float* qb0 = (cs < 4) ? qbaseA : qbaseB;
        const int ccb = (cs & 3)*32 + g*8;
        float qv[8];
        #pragma unroll
        for (int j = 0; j < 8; j++)
            qv[j] = qb0[(size_t)(ccb + j)*Mt];
        bf16x8 qh, ql;
        #pragma unroll
        for (int j = 0; j < 8; j++) {
            ushort hq, lq; split2(qv[j], hq, lq);
            qh[j] = (short)hq; ql[j] = (short)lq;
        }
        #pragma unroll
        for (int nt = 0; nt < 16; nt++) {
            const bf16x8 kh = *(const bf16x8*)(khp + nt*4096 + cs*32);
            const bf16x8 kl = *(const bf16x8*)(klp + nt*4096 + cs*32);
            acc[nt] = __builtin_amdgcn_mfma_f32_16x16x32_bf16(kh, qh, acc[nt], 0, 0, 0);
            acc[nt] = __builtin_amdgcn_mfma_f32_16x16x32_bf16(kh, ql, acc[nt], 0, 0, 0);
            acc[nt] = __builtin_amdgcn_mfma_f32_16x16x32_bf16(kl, qh, acc[nt], 0, 0, 0);
        }
    }

    __syncthreads();   // G-table / fxs ready

    // ---- bias + softmax (row m is wave-local across the 4 g-lanes)
    const int dm = w*16 + l15;
    float mx = -1e30f;
    #pragma unroll
    for (int nt = 0; nt < 16; nt++) {
        #pragma unroll
        for (int r = 0; r < 4; r++) {
            const int n = nt*16 + g*4 + r;
            const float g0 = Gt[n*GS + dm];
            const float g1 = Gt[n*GS + dm + 1];
            const float bias = g0 + fxs[n]*(g1 - g0);
            const float s = SCALE_F*acc[nt][r] + bias;
            acc[nt][r] = s;
            mx = fmaxf(mx, s);
        }
    }
    mx = fmaxf(mx, __shfl_xor(mx, 16, 64));
    mx = fmaxf(mx, __shfl_xor(mx, 32, 64));
    float sum = 0.f;
    #pragma unroll
    for (int nt = 0; nt < 16; nt++)
        #pragma unroll
        for (int r = 0; r < 4; r++) {
            const float e = __expf(acc[nt][r] - mx);
            acc[nt][r] = e;
            sum += e;
        }
    sum += __shfl_xor(sum, 16, 64);
    sum += __shfl_xor(sum, 32, 64);
    const float inv = 1.f / sum;

    // ---- pack P to bf16 hi/lo word pairs (per nt: words [r0|r1], [r2|r3])
    uint hU0[16], hU1[16], lU0[16], lU1[16];
    #pragma unroll
    for (int nt = 0; nt < 16; nt++) {
        ushort ph[4], pl[4];
        #pragma unroll
        for (int r = 0; r < 4; r++) split2(acc[nt][r] * inv, ph[r], pl[r]);
        hU0[nt] = (uint)ph[0] | ((uint)ph[1] << 16);
        hU1[nt] = (uint)ph[2] | ((uint)ph[3] << 16);
        lU0[nt] = (uint)pl[0] | ((uint)pl[1] << 16);
        lU1[nt] = (uint)pl[2] | ((uint)pl[3] << 16);
    }

    // ---- PV with in-register P redistribution
    f32x4 acc2[16];
    #pragma unroll
    for (int jt = 0; jt < 16; jt++) acc2[jt] = (f32x4){0.f, 0.f, 0.f, 0.f};
    const int srcA = (((2*g)     & 3) << 4) | l15;
    const int srcB = (((2*g + 1) & 3) << 4) | l15;
    const bool hi2 = (g >> 1) & 1;
    const ushort* vhp = VsH + ((size_t)bh*256 + l15)*256 + g*8;
    const ushort* vlp = VsL + ((size_t)bh*256 + l15)*256 + g*8;
    #pragma unroll
    for (int cs = 0; cs < 8; cs++) {
        uint A00 = shfu(hU0[2*cs], srcA), A01 = shfu(hU0[2*cs+1], srcA);
        uint A10 = shfu(hU1[2*cs], srcA), A11 = shfu(hU1[2*cs+1], srcA);
        uint B00 = shfu(hU0[2*cs], srcB), B01 = shfu(hU0[2*cs+1], srcB);
        uint B10 = shfu(hU1[2*cs], srcB), B11 = shfu(hU1[2*cs+1], srcB);
        const bf16x8 ph = pack4(hi2 ? A01 : A00, hi2 ? A11 : A10,
                                hi2 ? B01 : B00, hi2 ? B11 : B10);
        A00 = shfu(lU0[2*cs], srcA); A01 = shfu(lU0[2*cs+1], srcA);
        A10 = shfu(lU1[2*cs], srcA); A11 = shfu(lU1[2*cs+1], srcA);
        B00 = shfu(lU0[2*cs], srcB); B01 = shfu(lU0[2*cs+1], srcB);
        B10 = shfu(lU1[2*cs], srcB); B11 = shfu(lU1[2*cs+1], srcB);
        const bf16x8 pl = pack4(hi2 ? A01 : A00, hi2 ? A11 : A10,
                                hi2 ? B01 : B00, hi2 ? B11 : B10);
        #pragma unroll
        for (int jt = 0; jt < 16; jt++) {
            const bf16x8 vh = *(const bf16x8*)(vhp + jt*4096 + cs*32);
            const bf16x8 vl = *(const bf16x8*)(vlp + jt*4096 + cs*32);
            acc2[jt] = __builtin_amdgcn_mfma_f32_16x16x32_bf16(vh, ph, acc2[jt], 0, 0, 0);
            acc2[jt] = __builtin_amdgcn_mfma_f32_16x16x32_bf16(vh, pl, acc2[jt], 0, 0, 0);
            acc2[jt] = __builtin_amdgcn_mfma_f32_16x16x32_bf16(vl, ph, acc2[jt], 0, 0, 0);
        }
    }

    // ---- epilogue: token-major O (bh, M, D)
    const size_t rowbase = ((size_t)bh*Mt + mcol)*Dd;
    #pragma unroll
    for (int jt = 0; jt < 16; jt++) {
        const float4 o = make_float4(acc2[jt][0], acc2[jt][1], acc2[jt][2], acc2[jt][3]);
        const int jv0 = jt*16 + g*4;
        if (jt < 8) *(float4*)(Oa + rowbase + jv0) = o;
        else        *(float4*)(Ob + rowbase + jv0 - 128) = o;
    }
}

// ---------------------------------------------------------------------------
// Complex whitening LN (attention branch) + residual from (B,C,M) input.
// grid (Mt/32, BHt), block 256. X2 written token-major.
// ---------------------------------------------------------------------------
__global__ __launch_bounds__(256)
void k_cln_attn(const float* __restrict__ Oa, const float* __restrict__ Ob,
                const float* __restrict__ Xa, const float* __restrict__ Xb,
                const float* __restrict__ Pgrr, const float* __restrict__ Pgri,
                const float* __restrict__ Pgii, const float* __restrict__ Pbr,
                const float* __restrict__ Pbi,
                float* __restrict__ X2a, float* __restrict__ X2b)
{
    __shared__ float ra[32][132];
    __shared__ float rb[32][132];
    const int tid = threadIdx.x;
    const int m0 = blockIdx.x * 32;
    const int bh = blockIdx.y;
    const int b = bh >> 1, h = bh & 1;
    {
        const float* Xpa = Xa + ((size_t)b*Cc + h*Dd)*Mt + m0;
        const float* Xpb = Xb + ((size_t)b*Cc + h*Dd)*Mt + m0;
        for (int idx = tid; idx < 1024; idx += 256) {
            const int c = idx >> 3, jq = idx & 7;
            float4 a4 = *(const float4*)(Xpa + (size_t)c*Mt + jq*4);
            float4 b4 = *(const float4*)(Xpb + (size_t)c*Mt + jq*4);
            ra[jq*4+0][c] = a4.x; ra[jq*4+1][c] = a4.y;
            ra[jq*4+2][c] = a4.z; ra[jq*4+3][c] = a4.w;
            rb[jq*4+0][c] = b4.x; rb[jq*4+1][c] = b4.y;
            rb[jq*4+2][c] = b4.z; rb[jq*4+3][c] = b4.w;
        }
    }
    __syncthreads();
    const int wave = tid >> 6, lane = tid & 63;
    const float grr0 = Pgrr[lane], grr1 = Pgrr[lane+64];
    const float gri0 = Pgri[lane], gri1 = Pgri[lane+64];
    const float gii0 = Pgii[lane], gii1 = Pgii[lane+64];
    const float br0  = Pbr[lane],  br1  = Pbr[lane+64];
    const float bi0  = Pbi[lane],  bi1  = Pbi[lane+64];
    for (int r = wave; r < 32; r += 4) {
        const size_t rowoff = ((size_t)bh*Mt + m0 + r)*Dd;
        float a0 = Oa[rowoff + lane], a1 = Oa[rowoff + lane + 64];
        float c0 = Ob[rowoff + lane], c1 = Ob[rowoff + lane + 64];
        const float ma = wsum64(a0 + a1) * (1.f/128.f);
        const float mb = wsum64(c0 + c1) * (1.f/128.f);
        a0 -= ma; a1 -= ma; c0 -= mb; c1 -= mb;
        const float vrr = wsum64(a0*a0 + a1*a1) * (1.f/128.f) + 1e-20f;
        const float vii = wsum64(c0*c0 + c1*c1) * (1.f/128.f) + 1e-20f;
        const float vri = wsum64(a0*c0 + a1*c1) * (1.f/128.f);
        const float s = sqrtf(fmaxf(vrr*vii - vri*vri, 0.f));
        const float t = sqrtf(vrr + vii + 2.f*s);
        const float inv = 1.f / (s*t);
        const float wrr = (vii + s)*inv, wii = (vrr + s)*inv, wri = -vri*inv;
        const float na0 = wrr*a0 + wri*c0, nb0 = wri*a0 + wii*c0;
        const float na1 = wrr*a1 + wri*c1, nb1 = wri*a1 + wii*c1;
        X2a[rowoff + lane]      = ra[r][lane]    + grr0*na0 + gri0*nb0 + br0;
        X2a[rowoff + lane + 64] = ra[r][lane+64] + grr1*na1 + gri1*nb1 + br1;
        X2b[rowoff + lane]      = rb[r][lane]    + gri0*na0 + gii0*nb0 + bi0;
        X2b[rowoff + lane + 64] = rb[r][lane+64] + gri1*na1 + gii1*nb1 + bi1;
    }
}

// ---------------------------------------------------------------------------
// Complex linear, FULL-WIDTH blocks (64 rows x all 128 cols):
// Ha = A@Wr^T - B@Wi^T + br ; Hb = A@Wi^T + B@Wr^T + bi ; optional relu.
// Safe for in-place (Ha==A, Hb==B): a block reads only its own 64 rows, and
// all global reads complete (k-loop) before the epilogue stores.
// grid (BHt*Mt/64), block 256
// ---------------------------------------------------------------------------
__global__ __launch_bounds__(256)
void k_ffn_full(const float* __restrict__ A, const float* __restrict__ Bm,
                const float* __restrict__ Wr, const float* __restrict__ Wi,
                const float* __restrict__ br, const float* __restrict__ bi,
                float* __restrict__ Ha, float* __restrict__ Hb, int relu)
{
    __shared__ float as_[16][64], bs_[16][64];
    __shared__ float wrs[16][128], wis[16][128];
    const int tid = threadIdx.x;
    const size_t r0 = (size_t)blockIdx.x * 64;
    const int tr = tid >> 4;   // 0..15: rows tr*4+ii
    const int tn = tid & 15;   // 0..15: cols tn*8+jj
    float accr[4][8] = {{0.f}}, acci[4][8] = {{0.f}};
    for (int k0 = 0; k0 < Dd; k0 += 16) {
        {
            const int row = tid >> 2, kq = tid & 3;
            float4 a4 = *(const float4*)(A  + (r0 + row)*Dd + k0 + kq*4);
            float4 b4 = *(const float4*)(Bm + (r0 + row)*Dd + k0 + kq*4);
            as_[kq*4+0][row] = a4.x; as_[kq*4+1][row] = a4.y;
            as_[kq*4+2][row] = a4.z; as_[kq*4+3][row] = a4.w;
            bs_[kq*4+0][row] = b4.x; bs_[kq*4+1][row] = b4.y;
            bs_[kq*4+2][row] = b4.z; bs_[kq*4+3][row] = b4.w;
            #pragma unroll
            for (int rep = 0; rep < 2; rep++) {
                const int wrow = row + rep*64;
                float4 r4 = *(const float4*)(Wr + (size_t)wrow*Dd + k0 + kq*4);
                float4 i4 = *(const float4*)(Wi + (size_t)wrow*Dd + k0 + kq*4);
                wrs[kq*4+0][wrow] = r4.x; wrs[kq*4+1][wrow] = r4.y;
                wrs[kq*4+2][wrow] = r4.z; wrs[kq*4+3][wrow] = r4.w;
                wis[kq*4+0][wrow] = i4.x; wis[kq*4+1][wrow] = i4.y;
                wis[kq*4+2][wrow] = i4.z; wis[kq*4+3][wrow] = i4.w;
            }
        }
        __syncthreads();
        #pragma unroll
        for (int kk = 0; kk < 16; kk++) {
            float4 a4 = *(const float4*)&as_[kk][tr*4];
            float4 b4 = *(const float4*)&bs_[kk][tr*4];
            float4 r40 = *(const float4*)&wrs[kk][tn*8];
            float4 r41 = *(const float4*)&wrs[kk][tn*8+4];
            float4 i40 = *(const float4*)&wis[kk][tn*8];
            float4 i41 = *(const float4*)&wis[kk][tn*8+4];
            float av[4] = {a4.x,a4.y,a4.z,a4.w};
            float bv[4] = {b4.x,b4.y,b4.z,b4.w};
            float rv[8] = {r40.x,r40.y,r40.z,r40.w,r41.x,r41.y,r41.z,r41.w};
            float iv[8] = {i40.x,i40.y,i40.z,i40.w,i41.x,i41.y,i41.z,i41.w};
            #pragma unroll
            for (int ii = 0; ii < 4; ii++)
                #pragma unroll
                for (int jj = 0; jj < 8; jj++) {
                    accr[ii][jj] += av[ii]*rv[jj] - bv[ii]*iv[jj];
                    acci[ii][jj] += av[ii]*iv[jj] + bv[ii]*rv[jj];
                }
        }
        __syncthreads();
    }
    #pragma unroll
    for (int ii = 0; ii < 4; ii++) {
        const size_t row = r0 + tr*4 + ii;
        #pragma unroll
        for (int jq = 0; jq < 2; jq++) {
            float4 vr, vi;
            float* pr = &vr.x; float* pi = &vi.x;
            #pragma unroll
            for (int q = 0; q < 4; q++) {
                const int n = tn*8 + jq*4 + q;
                float hr = accr[ii][jq*4+q] + br[n];
                float hi = acci[ii][jq*4+q] + bi[n];
                if (relu) { hr = fmaxf(hr, 0.f); hi = fmaxf(hi, 0.f); }
                pr[q] = hr; pi[q] = hi;
            }
            *(float4*)(Ha + row*Dd + tn*8 + jq*4) = vr;
            *(float4*)(Hb + row*Dd + tn*8 + jq*4) = vi;
        }
    }
}

// ---------------------------------------------------------------------------
// Complex whitening LN (FFN branch) + residual (token-major) + transpose out
// to (B,C,M). grid (Mt/32, BHt), block 256
// ---------------------------------------------------------------------------
__global__ __launch_bounds__(256)
void k_cln_ffn(const float* __restrict__ Ha2, const float* __restrict__ Hb2,
               const float* __restrict__ X2a, const float* __restrict__ X2b,
               const float* __restrict__ Pgrr, const float* __restrict__ Pgri,
               const float* __restrict__ Pgii, const float* __restrict__ Pbr,
               const float* __restrict__ Pbi,
               float* __restrict__ OutA, float* __restrict__ OutB)
{
    __shared__ float oA[128][36];
    __shared__ float oB[128][36];
    const int tid = threadIdx.x;
    const int m0 = blockIdx.x * 32;
    const int bh = blockIdx.y;
    const int b = bh >> 1, h = bh & 1;
    const int wave = tid >> 6, lane = tid & 63;
    const float grr0 = Pgrr[lane], grr1 = Pgrr[lane+64];
    const float gri0 = Pgri[lane], gri1 = Pgri[lane+64];
    const float gii0 = Pgii[lane], gii1 = Pgii[lane+64];
    const float br0  = Pbr[lane],  br1  = Pbr[lane+64];
    const float bi0  = Pbi[lane],  bi1  = Pbi[lane+64];
    for (int r = wave; r < 32; r += 4) {
        const size_t rowoff = ((size_t)bh*Mt + m0 + r)*Dd;
        float a0 = Ha2[rowoff + lane], a1 = Ha2[rowoff + lane + 64];
        float c0 = Hb2[rowoff + lane], c1 = Hb2[rowoff + lane + 64];
        const float ma = wsum64(a0 + a1) * (1.f/128.f);
        const float mb = wsum64(c0 + c1) * (1.f/128.f);
        a0 -= ma; a1 -= ma; c0 -= mb; c1 -= mb;
        const float vrr = wsum64(a0*a0 + a1*a1) * (1.f/128.f) + 1e-20f;
        const float vii = wsum64(c0*c0 + c1*c1) * (1.f/128.f) + 1e-20f;
        const float vri = wsum64(a0*c0 + a1*c1) * (1.f/128.f);
        const float s = sqrtf(fmaxf(vrr*vii - vri*vri, 0.f));
        const float t = sqrtf(vrr + vii + 2.f*s);
        const float inv = 1.f / (s*t);
        const float wrr = (vii + s)*inv, wii = (vrr + s)*inv, wri = -vri*inv;
        const float na0 = wrr*a0 + wri*c0, nb0 = wri*a0 + wii*c0;
        const float na1 = wrr*a1 + wri*c1, nb1 = wri*a1 + wii*c1;
        oA[lane][r]    = X2a[rowoff + lane]      + grr0*na0 + gri0*nb0 + br0;
        oA[lane+64][r] = X2a[rowoff + lane + 64] + grr1*na1 + gri1*nb1 + br1;
        oB[lane][r]    = X2b[rowoff + lane]      + gri0*na0 + gii0*nb0 + bi0;
        oB[lane+64][r] = X2b[rowoff + lane + 64] + gri1*na1 + gii1*nb1 + bi1;
    }
    __syncthreads();
    const size_t obase = ((size_t)b*Cc + h*Dd)*Mt + m0;
    for (int idx = tid; idx < 1024; idx += 256) {
        const int c = idx >> 3, jq = idx & 7;
        *(float4*)(OutA + obase + (size_t)c*Mt + jq*4) = *(const float4*)&oA[c][jq*4];
        *(float4*)(OutB + obase + (size_t)c*Mt + jq*4) = *(const float4*)&oB[c][jq*4];
    }
}

// ---------------------------------------------------------------------------
extern "C" void kernel_launch(void* const* d_in, const int* in_sizes, int n_in,
                              void* d_out, int out_size, void* d_ws, size_t ws_size,
                              hipStream_t stream)
{
    const float* xA0 = (const float*)d_in[0];
    const float* xB0 = (const float*)d_in[1];
    const float* wq  = (const float*)d_in[2];
    const float* bq  = (const float*)d_in[3];
    const float* wk  = (const float*)d_in[4];
    const float* bk  = (const float*)d_in[5];
    const float* wv  = (const float*)d_in[6];
    const float* bv  = (const float*)d_in[7];
    const float* dww = (const float*)d_in[8];
    const float* dwb = (const float*)d_in[9];
    const float* lng = (const float*)d_in[10];
    const float* lnb = (const float*)d_in[11];
    const float* pw  = (const float*)d_in[12];
    const float* f1wr = (const float*)d_in[13];
    const float* f1wi = (const float*)d_in[14];
    const float* f1br = (const float*)d_in[15];
    const float* f1bi = (const float*)d_in[16];
    const float* f2wr = (const float*)d_in[17];
    const float* f2wi = (const float*)d_in[18];
    const float* f2br = (const float*)d_in[19];
    const float* f2bi = (const float*)d_in[20];
    const float* lgrr = (const float*)d_in[21];
    const float* lgri = (const float*)d_in[22];
    const float* lgii = (const float*)d_in[23];
    const float* lbr  = (const float*)d_in[24];
    const float* lbi  = (const float*)d_in[25];
    const float* rpe  = (const float*)d_in[26];

    float* ws = (float*)d_ws;
    const size_t NB = (size_t)Bz * Cc * Mt;     // 16777216 floats (64 MB)
    const size_t SC = (size_t)Bz * Cc * NSs;    // 262144 floats (1 MB)
    // Compact layout: 2 big pairs (P: Q then X2; R: O then H1/H2) = 256 MB,
    // plus ~11 MB of small buffers. Layer chaining goes through d_out.
    float* Pa  = ws;        float* Pb  = Pa  + NB;
    float* Ra  = Pb  + NB;  float* Rb  = Ra  + NB;
    float* Ya  = Rb  + NB;  float* Yb  = Ya  + SC;
    float* XsA = Yb  + SC;  float* XsB = XsA + SC;
    float* Kab = XsB + SC;  float* Kbb = Kab + SC;
    float* Vab = Kbb + SC;  float* Vbb = Vab + SC;
    float* Sp0 = Vbb + SC;  float* Sp1 = Sp0 + SC;  // bf16 K split regions
    float* PosA = Sp1 + SC; float* PosB = PosA + (size_t)Bz*NSs*2;

    // bf16 hi/lo buffers (each 8*256*256 ushorts = 1 MB):
    // K reuses the two spare SC regions; V reuses Ya/Yb (dead after k_lnpw,
    // and k_vsplit runs after k_lnpw in program order).
    ushort* KtH = (ushort*)Sp0;
    ushort* KtL = (ushort*)Sp1;
    ushort* VsH = (ushort*)Ya;
    ushort* VsL = (ushort*)Yb;

    float* outAf = (float*)d_out;
    float* outBf = outAf + NB;

    for (int l = 0; l < LAYERS; l++) {
        const float* pwq = wq + (size_t)l*Cc*Cc;
        const float* pbq = bq + (size_t)l*Cc;
        const float* pwk = wk + (size_t)l*Cc*Cc;
        const float* pbk = bk + (size_t)l*Cc;
        const float* pwv = wv + (size_t)l*Cc*Cc;
        const float* pbv = bv + (size_t)l*Cc;
        const float* pdww = dww + (size_t)l*Cc*81;
        const float* pdwb = dwb + (size_t)l*Cc;
        const float* plng = lng + (size_t)l*Cc;
        const float* plnb = lnb + (size_t)l*Cc;
        const float* ppw  = pw  + (size_t)l*2*Cc;
        const float* p1wr = f1wr + (size_t)l*Dd*Dd;
        const float* p1wi = f1wi + (size_t)l*Dd*Dd;
        const float* p1br = f1br + (size_t)l*Dd;
        const float* p1bi = f1bi + (size_t)l*Dd;
        const float* p2wr = f2wr + (size_t)l*Dd*Dd;
        const float* p2wi = f2wi + (size_t)l*Dd*Dd;
        const float* p2br = f2br + (size_t)l*Dd;
        const float* p2bi = f2bi + (size_t)l*Dd;
        const float* g0rr = lgrr + (size_t)(l*2+0)*Dd;
        const float* g0ri = lgri + (size_t)(l*2+0)*Dd;
        const float* g0ii = lgii + (size_t)(l*2+0)*Dd;
        const float* g0br = lbr  + (size_t)(l*2+0)*Dd;
        const float* g0bi = lbi  + (size_t)(l*2+0)*Dd;
        const float* g1rr = lgrr + (size_t)(l*2+1)*Dd;
        const float* g1ri = lgri + (size_t)(l*2+1)*Dd;
        const float* g1ii = lgii + (size_t)(l*2+1)*Dd;
        const float* g1br = lbr  + (size_t)(l*2+1)*Dd;
        const float* g1bi = lbi  + (size_t)(l*2+1)*Dd;
        const float* prpe = rpe + (size_t)l*NHh*RPH*RPW;

        const float* inA = l ? outAf : xA0;
        const float* inB = l ? outBf : xB0;

        // Q -> P
        dim3 gP(Mt/64, Cc/64, Bz);
        k_proj<<<gP, 256, 0, stream>>>(inA, pwq, pbq, Pa, Mt);
        k_proj<<<gP, 256, 0, stream>>>(inB, pwq, pbq, Pb, Mt);

        dim3 gD(Cc, Bz);
        k_dwconv<<<gD, 256, 0, stream>>>(Pa, pdww, pdwb, Ya);
        k_dwconv<<<gD, 256, 0, stream>>>(Pb, pdww, pdwb, Yb);

        dim3 gL(NSs, Bz);
        k_lnpw<<<gL, 256, 0, stream>>>(Ya, plng, plnb, ppw, PosA);
        k_lnpw<<<gL, 256, 0, stream>>>(Yb, plng, plnb, ppw, PosB);

        dim3 gS(Cc, Bz);
        k_gsample<<<gS, 256, 0, stream>>>(inA, PosA, XsA);
        k_gsample<<<gS, 256, 0, stream>>>(inB, PosB, XsB);

        dim3 gKV(NSs/64, Cc/64, Bz);
        k_proj<<<gKV, 256, 0, stream>>>(XsA, pwk, pbk, Kab, NSs);
        k_proj<<<gKV, 256, 0, stream>>>(XsB, pwk, pbk, Kbb, NSs);
        k_proj<<<gKV, 256, 0, stream>>>(XsA, pwv, pbv, Vab, NSs);
        k_proj<<<gKV, 256, 0, stream>>>(XsB, pwv, pbv, Vbb, NSs);

        // bf16 hi/lo pre-splits for MFMA attention (Ya/Yb dead by now)
        dim3 gKs(NSs/64, BHt);
        k_ksplit<<<gKs, 256, 0, stream>>>(Kab, Kbb, KtH, KtL);
        k_vsplit<<<2048, 256, 0, stream>>>(Vab, Vbb, VsH, VsL);

        // attn: Q(P) -> O(R).  Q dead afterwards.
        dim3 gA(Mt/64, BHt);
        k_attn_mfma<<<gA, 256, 0, stream>>>(Pa, Pb, KtH, KtL, VsH, VsL,
                                            PosA, prpe, Ra, Rb);

        // cln_attn: O(R) + X(in) -> X2(P).  O dead afterwards.
        dim3 gC(Mt/32, BHt);
        k_cln_attn<<<gC, 256, 0, stream>>>(Ra, Rb, inA, inB,
                                           g0rr, g0ri, g0ii, g0br, g0bi, Pa, Pb);

        // fc1: X2(P) -> H1(R); fc2: H1(R) -> H2(R) in-place.
        dim3 gF((unsigned)((size_t)BHt*Mt/64));
        k_ffn_full<<<gF, 256, 0, stream>>>(Pa, Pb, p1wr, p1wi, p1br, p1bi, Ra, Rb, 1);
        k_ffn_full<<<gF, 256, 0, stream>>>(Ra, Rb, p2wr, p2wi, p2br, p2bi, Ra, Rb, 0);

        // cln_ffn: H2(R) + X2(P) -> layer output (d_out; safe: inA not read here)
        k_cln_ffn<<<gC, 256, 0, stream>>>(Ra, Rb, Pa, Pb,
                                          g1rr, g1ri, g1ii, g1br, g1bi, outAf, outBf);
    }
    (void)in_sizes; (void)n_in; (void)out_size; (void)ws_size;
}